// Round 1
// baseline (1384.353 us; speedup 1.0000x reference)
//
#include <hip/hip_runtime.h>
#include <hip/hip_bf16.h>

#define NDIM 256
#define NHEAD 8
#define DHEAD 32
#define QKVDIM 768
#define SCALE 0.17677669529663687f  // 32^-0.5

// C[M x N] = A[M x 256] * B[256 x N] + bias[N]
// BM=64 BN=64 BK=16, 256 threads, 4x4 micro-tile per thread.
__global__ void gemm_bias(const float* __restrict__ A, int lda,
                          const float* __restrict__ B, int ldb,
                          const float* __restrict__ bias,
                          float* __restrict__ C, int ldc,
                          int M, int N) {
    __shared__ float As[64][17];   // +1 pad: avoid 4-way bank conflict on column reads
    __shared__ float Bs[16][64];
    int tid = threadIdx.x;
    int tx = tid & 15, ty = tid >> 4;
    int blockRow = blockIdx.x * 64;
    int blockCol = blockIdx.y * 64;
    float acc[4][4] = {};
    for (int k0 = 0; k0 < 256; k0 += 16) {
        {   // A tile: 64 rows x 16 k, float4 per thread
            int r  = tid >> 2;          // 0..63
            int kk = (tid & 3) * 4;     // 0,4,8,12
            int grow = blockRow + r;
            float4 v = make_float4(0.f, 0.f, 0.f, 0.f);
            if (grow < M) v = *(const float4*)(A + (size_t)grow * lda + k0 + kk);
            As[r][kk + 0] = v.x; As[r][kk + 1] = v.y;
            As[r][kk + 2] = v.z; As[r][kk + 3] = v.w;
        }
        {   // B tile: 16 k-rows x 64 cols, float4 per thread
            int kr = tid >> 4;          // 0..15
            int c4 = (tid & 15) * 4;    // 0..60
            float4 v = *(const float4*)(B + (size_t)(k0 + kr) * ldb + blockCol + c4);
            *(float4*)&Bs[kr][c4] = v;
        }
        __syncthreads();
        #pragma unroll
        for (int kk = 0; kk < 16; ++kk) {
            float a[4], b[4];
            #pragma unroll
            for (int i = 0; i < 4; i++) a[i] = As[ty * 4 + i][kk];
            float4 bv = *(float4*)&Bs[kk][tx * 4];
            b[0] = bv.x; b[1] = bv.y; b[2] = bv.z; b[3] = bv.w;
            #pragma unroll
            for (int i = 0; i < 4; i++)
                #pragma unroll
                for (int j = 0; j < 4; j++)
                    acc[i][j] += a[i] * b[j];
        }
        __syncthreads();
    }
    #pragma unroll
    for (int i = 0; i < 4; i++) {
        int grow = blockRow + ty * 4 + i;
        if (grow >= M) continue;
        #pragma unroll
        for (int j = 0; j < 4; j++) {
            int gcol = blockCol + tx * 4 + j;
            C[(size_t)grow * ldc + gcol] = acc[i][j] + bias[gcol];
        }
    }
}

// One 32-lane group per edge; 8 heads sequential. Accumulates un-normalized
// softmax numerator and denominator (max-shift dropped: scores ~N(0,1), no
// f32 overflow; softmax is shift-invariant).
__global__ void edge_pass(const float* __restrict__ qkv,
                          const int* __restrict__ src,
                          const int* __restrict__ dst,
                          float* __restrict__ num,    // [N][8][32]
                          float* __restrict__ denom,  // [N][8]
                          int E) {
    int gid  = threadIdx.x >> 5;   // 0..7
    int lane = threadIdx.x & 31;
    int e = blockIdx.x * 8 + gid;
    if (e >= E) return;
    int si = src[e], di = dst[e];
    const float* qrow = qkv + (size_t)di * QKVDIM;          // q of dst
    const float* krow = qkv + (size_t)si * QKVDIM + 256;    // k of src
    const float* vrow = qkv + (size_t)si * QKVDIM + 512;    // v of src
    float* nrow = num + (size_t)di * NDIM;
    #pragma unroll
    for (int head = 0; head < NHEAD; ++head) {
        float p = qrow[head * DHEAD + lane] * krow[head * DHEAD + lane];
        #pragma unroll
        for (int m = 16; m >= 1; m >>= 1) p += __shfl_xor(p, m);
        float s = __expf(p * SCALE);
        atomicAdd(nrow + head * DHEAD + lane, s * vrow[head * DHEAD + lane]);
        if (lane == 0) atomicAdd(denom + (size_t)di * NHEAD + head, s);
    }
}

// tmp[n, d*H + h] = num[n, h, d] / denom[n, h] + h_in[n, d*H + h]
// tmp written into the (dead) q region of the qkv buffer, stride 768.
__global__ void finalize(const float* __restrict__ num,
                         const float* __restrict__ denom,
                         const float* __restrict__ h_in,
                         float* __restrict__ tmp) {
    int n = blockIdx.x;
    int c = threadIdx.x;             // 0..255 ; c = d*H + head
    int head = c & 7;
    int d = c >> 3;
    float de = denom[(size_t)n * NHEAD + head];
    float v  = num[(size_t)n * NDIM + head * DHEAD + d];
    float val = (de > 0.f) ? (v / de) : 0.f;
    tmp[(size_t)n * QKVDIM + c] = val + h_in[(size_t)n * NDIM + c];
}

extern "C" void kernel_launch(void* const* d_in, const int* in_sizes, int n_in,
                              void* d_out, int out_size, void* d_ws, size_t ws_size,
                              hipStream_t stream) {
    const float* h     = (const float*)d_in[0];
    const int*   src   = (const int*)d_in[1];
    const int*   dst   = (const int*)d_in[2];
    const float* W_qkv = (const float*)d_in[3];
    const float* b_qkv = (const float*)d_in[4];
    const float* W_out = (const float*)d_in[5];
    const float* b_out = (const float*)d_in[6];
    float* out = (float*)d_out;

    int N = in_sizes[0] / NDIM;
    int E = in_sizes[1];

    float* qkv   = (float*)d_ws;                        // N*768
    float* num   = qkv + (size_t)N * QKVDIM;            // N*256
    float* denom = num + (size_t)N * NDIM;              // N*8

    // zero accumulators (num + denom contiguous)
    hipMemsetAsync(num, 0, (size_t)N * (NDIM + NHEAD) * sizeof(float), stream);

    dim3 g1((N + 63) / 64, QKVDIM / 64);
    gemm_bias<<<g1, 256, 0, stream>>>(h, NDIM, W_qkv, QKVDIM, b_qkv, qkv, QKVDIM, N, QKVDIM);

    edge_pass<<<(E + 7) / 8, 256, 0, stream>>>(qkv, src, dst, num, denom, E);

    finalize<<<N, 256, 0, stream>>>(num, denom, h, qkv);

    dim3 g2((N + 63) / 64, NDIM / 64);
    gemm_bias<<<g2, 256, 0, stream>>>(qkv, QKVDIM, W_out, NDIM, b_out, out, NDIM, N, NDIM);
}

// Round 2
// 746.719 us; speedup vs baseline: 1.8539x; 1.8539x over previous
//
#include <hip/hip_runtime.h>
#include <hip/hip_bf16.h>

#define NDIM 256
#define NHEAD 8
#define DHEAD 32
#define QKVDIM 768
#define SCALE 0.17677669529663687f  // 32^-0.5

// C[M x N] = A[M x 256] * B[256 x N] + bias[N]
// BM=64 BN=64 BK=16, 256 threads, 4x4 micro-tile per thread.
__global__ void gemm_bias(const float* __restrict__ A, int lda,
                          const float* __restrict__ B, int ldb,
                          const float* __restrict__ bias,
                          float* __restrict__ C, int ldc,
                          int M, int N) {
    __shared__ float As[64][17];
    __shared__ float Bs[16][64];
    int tid = threadIdx.x;
    int tx = tid & 15, ty = tid >> 4;
    int blockRow = blockIdx.x * 64;
    int blockCol = blockIdx.y * 64;
    float acc[4][4] = {};
    for (int k0 = 0; k0 < 256; k0 += 16) {
        {
            int r  = tid >> 2;
            int kk = (tid & 3) * 4;
            int grow = blockRow + r;
            float4 v = make_float4(0.f, 0.f, 0.f, 0.f);
            if (grow < M) v = *(const float4*)(A + (size_t)grow * lda + k0 + kk);
            As[r][kk + 0] = v.x; As[r][kk + 1] = v.y;
            As[r][kk + 2] = v.z; As[r][kk + 3] = v.w;
        }
        {
            int kr = tid >> 4;
            int c4 = (tid & 15) * 4;
            float4 v = *(const float4*)(B + (size_t)(k0 + kr) * ldb + blockCol + c4);
            *(float4*)&Bs[kr][c4] = v;
        }
        __syncthreads();
        #pragma unroll
        for (int kk = 0; kk < 16; ++kk) {
            float a[4], b[4];
            #pragma unroll
            for (int i = 0; i < 4; i++) a[i] = As[ty * 4 + i][kk];
            float4 bv = *(float4*)&Bs[kk][tx * 4];
            b[0] = bv.x; b[1] = bv.y; b[2] = bv.z; b[3] = bv.w;
            #pragma unroll
            for (int i = 0; i < 4; i++)
                #pragma unroll
                for (int j = 0; j < 4; j++)
                    acc[i][j] += a[i] * b[j];
        }
        __syncthreads();
    }
    #pragma unroll
    for (int i = 0; i < 4; i++) {
        int grow = blockRow + ty * 4 + i;
        if (grow >= M) continue;
        #pragma unroll
        for (int j = 0; j < 4; j++) {
            int gcol = blockCol + tx * 4 + j;
            C[(size_t)grow * ldc + gcol] = acc[i][j] + bias[gcol];
        }
    }
}

// ---------- CSR build ----------
__global__ void count_dst(const int* __restrict__ dst, int* __restrict__ counts, int E) {
    int i = blockIdx.x * blockDim.x + threadIdx.x;
    if (i < E) atomicAdd(&counts[dst[i]], 1);
}

// Single-workgroup exclusive scan, 1024 threads, wave-level shfl scan.
__global__ void scan_offsets(const int* __restrict__ counts, int* __restrict__ offsets, int N) {
    __shared__ int wsum[16];
    __shared__ int carry;
    int tid = threadIdx.x;
    int lane = tid & 63;
    int wid = tid >> 6;
    if (tid == 0) carry = 0;
    __syncthreads();
    for (int base = 0; base < N; base += 1024) {
        int i = base + tid;
        int v = (i < N) ? counts[i] : 0;
        int x = v;
        #pragma unroll
        for (int d = 1; d < 64; d <<= 1) {
            int y = __shfl_up(x, d);
            if (lane >= d) x += y;
        }
        if (lane == 63) wsum[wid] = x;
        __syncthreads();
        if (wid == 0 && lane < 16) {
            int w = wsum[lane];
            #pragma unroll
            for (int d = 1; d < 16; d <<= 1) {
                int y = __shfl_up(w, d);
                if (lane >= d) w += y;
            }
            wsum[lane] = w;   // inclusive scan of wave sums
        }
        __syncthreads();
        int pre = carry + (wid ? wsum[wid - 1] : 0);
        if (i < N) offsets[i] = pre + x - v;   // exclusive
        int total = wsum[15];
        __syncthreads();
        if (tid == 0) carry += total;
        __syncthreads();
    }
    if (tid == 0) offsets[N] = carry;
}

__global__ void copy_cursor(const int* __restrict__ offsets, int* __restrict__ cursor, int N) {
    int i = blockIdx.x * blockDim.x + threadIdx.x;
    if (i < N) cursor[i] = offsets[i];
}

__global__ void scatter_edges(const int* __restrict__ src, const int* __restrict__ dst,
                              int* __restrict__ cursor, int* __restrict__ csr_src, int E) {
    int i = blockIdx.x * blockDim.x + threadIdx.x;
    if (i < E) {
        int d = dst[i];
        int pos = atomicAdd(&cursor[d], 1);
        csr_src[pos] = src[i];
    }
}

// ---------- per-node attention: one 64-lane wave per dst node ----------
// lane covers dims [4*lane, 4*lane+4); head = lane>>3 (8 lanes per head).
// No atomics: num/denom accumulate in registers. Writes normalized,
// head-transposed, residual-added row into tmp (q region of qkv, stride 768).
__global__ void node_attn(const float* __restrict__ qkv,
                          const int* __restrict__ offsets,
                          const int* __restrict__ csr_src,
                          const float* __restrict__ h_in,
                          float* __restrict__ tmp, int N) {
    int wid = threadIdx.x >> 6;
    int lane = threadIdx.x & 63;
    int n = blockIdx.x * 4 + wid;
    if (n >= N) return;
    int beg = offsets[n], end = offsets[n + 1];
    const float4 q4 = *(const float4*)(qkv + (size_t)n * QKVDIM + lane * 4);
    float4 acc = make_float4(0.f, 0.f, 0.f, 0.f);
    float den = 0.f;
    for (int i = beg; i < end; ++i) {
        int s = csr_src[i];
        const float* kb = qkv + (size_t)s * QKVDIM + 256 + lane * 4;
        float4 k4 = *(const float4*)kb;
        float4 v4 = *(const float4*)(kb + 256);
        float p = q4.x * k4.x + q4.y * k4.y + q4.z * k4.z + q4.w * k4.w;
        p += __shfl_xor(p, 1);
        p += __shfl_xor(p, 2);
        p += __shfl_xor(p, 4);   // now all 8 lanes of the head hold the dot
        float sc = __expf(p * SCALE);
        den += sc;
        acc.x += sc * v4.x; acc.y += sc * v4.y;
        acc.z += sc * v4.z; acc.w += sc * v4.w;
    }
    float inv = (end > beg) ? (1.0f / den) : 0.f;
    int head = lane >> 3;
    int dl = (lane & 7) * 4;     // local dim within head
    const float* hr = h_in + (size_t)n * NDIM;
    float* tr = tmp + (size_t)n * QKVDIM;
    float vals[4] = {acc.x, acc.y, acc.z, acc.w};
    #pragma unroll
    for (int j = 0; j < 4; j++) {
        int col = (dl + j) * NHEAD + head;   // d*H + h layout
        tr[col] = vals[j] * inv + hr[col];
    }
}

extern "C" void kernel_launch(void* const* d_in, const int* in_sizes, int n_in,
                              void* d_out, int out_size, void* d_ws, size_t ws_size,
                              hipStream_t stream) {
    const float* h     = (const float*)d_in[0];
    const int*   src   = (const int*)d_in[1];
    const int*   dst   = (const int*)d_in[2];
    const float* W_qkv = (const float*)d_in[3];
    const float* b_qkv = (const float*)d_in[4];
    const float* W_out = (const float*)d_in[5];
    const float* b_out = (const float*)d_in[6];
    float* out = (float*)d_out;

    int N = in_sizes[0] / NDIM;
    int E = in_sizes[1];

    float* qkv     = (float*)d_ws;                  // N*768 f32
    int*   counts  = (int*)(qkv + (size_t)N * QKVDIM);
    int*   offsets = counts + N;                    // N+1
    int*   cursor  = offsets + N + 1;               // N
    int*   csr_src = cursor + N;                    // E

    hipMemsetAsync(counts, 0, (size_t)N * sizeof(int), stream);

    dim3 g1((N + 63) / 64, QKVDIM / 64);
    gemm_bias<<<g1, 256, 0, stream>>>(h, NDIM, W_qkv, QKVDIM, b_qkv, qkv, QKVDIM, N, QKVDIM);

    count_dst<<<(E + 255) / 256, 256, 0, stream>>>(dst, counts, E);
    scan_offsets<<<1, 1024, 0, stream>>>(counts, offsets, N);
    copy_cursor<<<(N + 255) / 256, 256, 0, stream>>>(offsets, cursor, N);
    scatter_edges<<<(E + 255) / 256, 256, 0, stream>>>(src, dst, cursor, csr_src, E);

    node_attn<<<(N + 3) / 4, 256, 0, stream>>>(qkv, offsets, csr_src, h, qkv, N);

    dim3 g2((N + 63) / 64, NDIM / 64);
    gemm_bias<<<g2, 256, 0, stream>>>(qkv, QKVDIM, W_out, NDIM, b_out, out, NDIM, N, NDIM);
}

// Round 3
// 387.136 us; speedup vs baseline: 3.5759x; 1.9288x over previous
//
#include <hip/hip_runtime.h>
#include <hip/hip_bf16.h>

#define NHEAD 8
#define SCALE 0.17677669529663687f  // 32^-0.5

typedef __attribute__((ext_vector_type(8))) short bf16x8;
typedef __attribute__((ext_vector_type(4))) float f32x4;

__device__ inline ushort f2b(float f) {          // f32 -> bf16 bits, RNE
    unsigned u = __float_as_uint(f);
    u += 0x7FFFu + ((u >> 16) & 1u);
    return (ushort)(u >> 16);
}
__device__ inline float b2f(ushort b) {          // bf16 bits -> f32 (exact)
    return __uint_as_float(((unsigned)b) << 16);
}

__device__ inline void load_lds16(const ushort* g, ushort* l) {
    __builtin_amdgcn_global_load_lds(
        (const __attribute__((address_space(1))) unsigned*)g,
        (__attribute__((address_space(3))) unsigned*)l, 16, 0, 0);
}

// ---------- conversions / weight prep ----------
__global__ void conv_bf16(const float* __restrict__ in, ushort* __restrict__ out, int n4) {
    int i = blockIdx.x * blockDim.x + threadIdx.x;
    if (i >= n4) return;
    float4 v = ((const float4*)in)[i];
    ushort4 o;
    o.x = f2b(v.x); o.y = f2b(v.y); o.z = f2b(v.z); o.w = f2b(v.w);
    ((ushort4*)out)[i] = o;
}

// WTq[col][k] = bf16(W_qkv[k][col]);  W_qkv is [256][768]
__global__ void transpose_wqkv(const float* __restrict__ W, ushort* __restrict__ WT) {
    int col = blockIdx.x;      // 0..767
    int k   = threadIdx.x;     // 0..255
    WT[(size_t)col * 256 + k] = f2b(W[(size_t)k * 768 + col]);
}

// WTo[col][c'] = bf16(W_out[pi(c')][col]), pi(c') = (c'&31)*8 + (c'>>5)
// (absorbs the head-transpose of the attention output into the weight)
__global__ void transpose_wout(const float* __restrict__ W, ushort* __restrict__ WT) {
    int col = blockIdx.x;      // 0..255
    int cp  = threadIdx.x;     // 0..255
    int c   = ((cp & 31) * 8) + (cp >> 5);
    WT[(size_t)col * 256 + cp] = f2b(W[(size_t)c * 256 + col]);
}

// ---------- MFMA GEMM: C[M x Ncols] = A[M x 256] * BT[Ncols x 256]^T + bias ----------
// 128x128 tile, BK=32, 4 waves, 16x16x32 bf16 MFMA, global_load_lds width-16.
// MODE 0: Cf[row*256+col] = v               (GEMM2 -> out)
// MODE 1: col<256 -> q f32 [row*256+col]; col>=256 -> kv bf16 [row*512+col-256]
template<int MODE>
__global__ __launch_bounds__(256)
void gemm_mfma(const ushort* __restrict__ A,
               const ushort* __restrict__ BT,
               const float*  __restrict__ bias,
               float* __restrict__ Cf, ushort* __restrict__ Ckv,
               int M) {
    __shared__ ushort As[128 * 32];
    __shared__ ushort Bs[128 * 32];
    const int tid  = threadIdx.x;
    const int wid  = tid >> 6;
    const int lane = tid & 63;
    const int l15  = lane & 15, l4 = lane >> 4;
    const int wr = wid >> 1, wc = wid & 1;
    const int blockRow = blockIdx.x * 128;
    const int blockCol = blockIdx.y * 128;

    f32x4 acc[4][4] = {};

    for (int k0 = 0; k0 < 256; k0 += 32) {
        #pragma unroll
        for (int t = 0; t < 2; ++t) {
            int c   = t * 256 + wid * 64 + lane;   // 16B-chunk index, lane-contiguous
            int row = c >> 2, ko = (c & 3) * 8;
            load_lds16(A  + (size_t)(blockRow + row) * 256 + k0 + ko,
                       As + (size_t)(t * 256 + wid * 64) * 8);
            load_lds16(BT + (size_t)(blockCol + row) * 256 + k0 + ko,
                       Bs + (size_t)(t * 256 + wid * 64) * 8);
        }
        __syncthreads();   // compiler drains vmcnt before s_barrier
        bf16x8 af[4], bfr[4];
        #pragma unroll
        for (int m = 0; m < 4; ++m)
            af[m] = *(const bf16x8*)&As[(wr * 64 + m * 16 + l15) * 32 + l4 * 8];
        #pragma unroll
        for (int n = 0; n < 4; ++n)
            bfr[n] = *(const bf16x8*)&Bs[(wc * 64 + n * 16 + l15) * 32 + l4 * 8];
        #pragma unroll
        for (int m = 0; m < 4; ++m)
            #pragma unroll
            for (int n = 0; n < 4; ++n)
                acc[m][n] = __builtin_amdgcn_mfma_f32_16x16x32_bf16(af[m], bfr[n], acc[m][n], 0, 0, 0);
        __syncthreads();
    }

    #pragma unroll
    for (int m = 0; m < 4; ++m) {
        #pragma unroll
        for (int r = 0; r < 4; ++r) {
            int row = blockRow + wr * 64 + m * 16 + l4 * 4 + r;   // C/D: row=(lane>>4)*4+reg
            if (row >= M) continue;
            #pragma unroll
            for (int n = 0; n < 4; ++n) {
                int col = blockCol + wc * 64 + n * 16 + l15;      // C/D: col=lane&15
                float v = acc[m][n][r] + bias[col];
                if (MODE == 0) {
                    Cf[(size_t)row * 256 + col] = v;
                } else {
                    if (col < 256) Cf[(size_t)row * 256 + col] = v;
                    else           Ckv[(size_t)row * 512 + (col - 256)] = f2b(v);
                }
            }
        }
    }
}

// ---------- CSR build ----------
__global__ void count_dst(const int* __restrict__ dst, int* __restrict__ counts, int E) {
    int i = blockIdx.x * blockDim.x + threadIdx.x;
    if (i < E) atomicAdd(&counts[dst[i]], 1);
}

__global__ void scan_offsets(const int* __restrict__ counts, int* __restrict__ offsets,
                             int* __restrict__ cursor, int N) {
    __shared__ int wsum[16];
    __shared__ int carry;
    int tid = threadIdx.x;
    int lane = tid & 63;
    int wid = tid >> 6;
    if (tid == 0) carry = 0;
    __syncthreads();
    for (int base = 0; base < N; base += 1024) {
        int i = base + tid;
        int v = (i < N) ? counts[i] : 0;
        int x = v;
        #pragma unroll
        for (int d = 1; d < 64; d <<= 1) {
            int y = __shfl_up(x, d);
            if (lane >= d) x += y;
        }
        if (lane == 63) wsum[wid] = x;
        __syncthreads();
        if (wid == 0 && lane < 16) {
            int w = wsum[lane];
            #pragma unroll
            for (int d = 1; d < 16; d <<= 1) {
                int y = __shfl_up(w, d);
                if (lane >= d) w += y;
            }
            wsum[lane] = w;
        }
        __syncthreads();
        int pre = carry + (wid ? wsum[wid - 1] : 0);
        if (i < N) { int off = pre + x - v; offsets[i] = off; cursor[i] = off; }
        int total = wsum[15];
        __syncthreads();
        if (tid == 0) carry += total;
        __syncthreads();
    }
    if (tid == 0) offsets[N] = carry;
}

__global__ void scatter_edges(const int* __restrict__ src, const int* __restrict__ dst,
                              int* __restrict__ cursor, int* __restrict__ csr_src, int E) {
    int i = blockIdx.x * blockDim.x + threadIdx.x;
    if (i < E) {
        int d = dst[i];
        int pos = atomicAdd(&cursor[d], 1);
        csr_src[pos] = src[i];
    }
}

// ---------- per-node attention: one wave per dst node ----------
// lane covers q/k/v cols lane*4..+3 (= head(lane>>3), d0=(lane&7)*4).
// Output written head-major (c' = head*32+d = lane*4+j, coalesced bf16);
// head-transpose absorbed into WTo. Residual gathered at ref col d*8+head.
__global__ void node_attn(const float* __restrict__ q,
                          const ushort* __restrict__ kvbf,
                          const int* __restrict__ offsets,
                          const int* __restrict__ csr_src,
                          const float* __restrict__ h_in,
                          ushort* __restrict__ h2,
                          int N) {
    int wid = threadIdx.x >> 6, lane = threadIdx.x & 63;
    int n = blockIdx.x * 4 + wid;
    if (n >= N) return;
    int beg = offsets[n], end = offsets[n + 1];
    const float4 q4 = *(const float4*)(q + (size_t)n * 256 + lane * 4);
    float ax = 0.f, ay = 0.f, az = 0.f, aw = 0.f, den = 0.f;
    for (int i = beg; i < end; ++i) {
        int s = csr_src[i];
        const ushort* kb = kvbf + (size_t)s * 512 + lane * 4;
        ushort4 ku = *(const ushort4*)kb;
        ushort4 vu = *(const ushort4*)(kb + 256);
        float p = q4.x * b2f(ku.x) + q4.y * b2f(ku.y) + q4.z * b2f(ku.z) + q4.w * b2f(ku.w);
        p += __shfl_xor(p, 1);
        p += __shfl_xor(p, 2);
        p += __shfl_xor(p, 4);     // 8 lanes of a head now hold the full 32-dot
        float sc = __expf(p * SCALE);
        den += sc;
        ax += sc * b2f(vu.x); ay += sc * b2f(vu.y);
        az += sc * b2f(vu.z); aw += sc * b2f(vu.w);
    }
    float inv = (end > beg) ? (1.0f / den) : 0.f;
    int head = lane >> 3;
    int d0 = (lane & 7) * 4;
    const float* hr = h_in + (size_t)n * 256;
    ushort4 o;
    o.x = f2b(ax * inv + hr[(d0 + 0) * 8 + head]);
    o.y = f2b(ay * inv + hr[(d0 + 1) * 8 + head]);
    o.z = f2b(az * inv + hr[(d0 + 2) * 8 + head]);
    o.w = f2b(aw * inv + hr[(d0 + 3) * 8 + head]);
    *(ushort4*)(h2 + (size_t)n * 256 + lane * 4) = o;
}

extern "C" void kernel_launch(void* const* d_in, const int* in_sizes, int n_in,
                              void* d_out, int out_size, void* d_ws, size_t ws_size,
                              hipStream_t stream) {
    const float* h     = (const float*)d_in[0];
    const int*   src   = (const int*)d_in[1];
    const int*   dst   = (const int*)d_in[2];
    const float* W_qkv = (const float*)d_in[3];
    const float* b_qkv = (const float*)d_in[4];
    const float* W_out = (const float*)d_in[5];
    const float* b_out = (const float*)d_in[6];
    float* out = (float*)d_out;

    int N = in_sizes[0] / 256;
    int E = in_sizes[1];
    int Mpad = (N + 127) & ~127;

    float*  q    = (float*)d_ws;                       // Mpad*256 f32
    ushort* kvbf = (ushort*)(q + (size_t)Mpad * 256);  // Mpad*512 bf16
    ushort* Abf  = kvbf + (size_t)Mpad * 512;          // Mpad*256 bf16 (reused as h2)
    ushort* WTq  = Abf + (size_t)Mpad * 256;           // 768*256
    ushort* WTo  = WTq + 768 * 256;                    // 256*256
    int* counts  = (int*)(WTo + 256 * 256);            // N
    int* offsets = counts + N;                         // N+1
    int* cursor  = offsets + N + 1;                    // N
    int* csr_src = cursor + N;                         // E

    hipMemsetAsync(counts, 0, (size_t)N * sizeof(int), stream);

    conv_bf16<<<(N * 64 + 255) / 256, 256, 0, stream>>>(h, Abf, N * 64);  // N*256/4 float4s
    transpose_wqkv<<<768, 256, 0, stream>>>(W_qkv, WTq);
    transpose_wout<<<256, 256, 0, stream>>>(W_out, WTo);

    dim3 g1(Mpad / 128, 6);
    gemm_mfma<1><<<g1, 256, 0, stream>>>(Abf, WTq, b_qkv, q, kvbf, N);

    count_dst<<<(E + 255) / 256, 256, 0, stream>>>(dst, counts, E);
    scan_offsets<<<1, 1024, 0, stream>>>(counts, offsets, cursor, N);
    scatter_edges<<<(E + 255) / 256, 256, 0, stream>>>(src, dst, cursor, csr_src, E);

    node_attn<<<(N + 3) / 4, 256, 0, stream>>>(q, kvbf, offsets, csr_src, h, Abf, N);

    dim3 g2(Mpad / 128, 2);
    gemm_mfma<0><<<g2, 256, 0, stream>>>(Abf, WTo, b_out, out, nullptr, N);
}

// Round 4
// 348.815 us; speedup vs baseline: 3.9687x; 1.1099x over previous
//
#include <hip/hip_runtime.h>
#include <hip/hip_bf16.h>

#define NHEAD 8
#define SCALE 0.17677669529663687f  // 32^-0.5

typedef __attribute__((ext_vector_type(8))) short bf16x8;
typedef __attribute__((ext_vector_type(4))) float f32x4;
typedef __attribute__((ext_vector_type(8))) unsigned short ushort8;

__device__ inline ushort f2b(float f) {          // f32 -> bf16 bits, RNE
    unsigned u = __float_as_uint(f);
    u += 0x7FFFu + ((u >> 16) & 1u);
    return (ushort)(u >> 16);
}
__device__ inline float b2f(ushort b) {          // bf16 bits -> f32 (exact)
    return __uint_as_float(((unsigned)b) << 16);
}

__device__ inline void load_lds16(const ushort* g, ushort* l) {
    __builtin_amdgcn_global_load_lds(
        (const __attribute__((address_space(1))) unsigned*)g,
        (__attribute__((address_space(3))) unsigned*)l, 16, 0, 0);
}

// ---------- conversions / weight prep ----------
__global__ void conv_bf16(const float* __restrict__ in, ushort* __restrict__ out, int n4) {
    int i = blockIdx.x * blockDim.x + threadIdx.x;
    if (i >= n4) return;
    float4 v = ((const float4*)in)[i];
    ushort4 o;
    o.x = f2b(v.x); o.y = f2b(v.y); o.z = f2b(v.z); o.w = f2b(v.w);
    ((ushort4*)out)[i] = o;
}

// WTq[col][k] = bf16(W_qkv[k][col]);  W_qkv is [256][768]
__global__ void transpose_wqkv(const float* __restrict__ W, ushort* __restrict__ WT) {
    int col = blockIdx.x;      // 0..767
    int k   = threadIdx.x;     // 0..255
    WT[(size_t)col * 256 + k] = f2b(W[(size_t)k * 768 + col]);
}

// WTo[col][c'] = bf16(W_out[pi(c')][col]), pi(c') = (c'&31)*8 + (c'>>5)
// (absorbs the head-transpose of the attention output into the weight)
__global__ void transpose_wout(const float* __restrict__ W, ushort* __restrict__ WT) {
    int col = blockIdx.x;      // 0..255
    int cp  = threadIdx.x;     // 0..255
    int c   = ((cp & 31) * 8) + (cp >> 5);
    WT[(size_t)col * 256 + cp] = f2b(W[(size_t)c * 256 + col]);
}

// ---------- MFMA GEMM: C = A[M x 256] * BT[Ncols x 256]^T + bias ----------
// 128x128 tile, BK=32, 4 waves, 16x16x32 bf16 MFMA, global_load_lds width-16.
// MODE 0: Cf[row*256+col] = v  (f32, GEMM2 -> out)
// MODE 1: col<256   -> qb bf16 [row*256+col]
//         col>=256  -> kv bf16 interleaved: k dim d -> (d>>2)*8+(d&3),
//                                           v dim d -> (d>>2)*8+4+(d&3)
template<int MODE>
__global__ __launch_bounds__(256)
void gemm_mfma(const ushort* __restrict__ A,
               const ushort* __restrict__ BT,
               const float*  __restrict__ bias,
               float* __restrict__ Cf,
               ushort* __restrict__ qb, ushort* __restrict__ kv,
               int M) {
    __shared__ ushort As[128 * 32];
    __shared__ ushort Bs[128 * 32];
    const int tid  = threadIdx.x;
    const int wid  = tid >> 6;
    const int lane = tid & 63;
    const int l15  = lane & 15, l4 = lane >> 4;
    const int wr = wid >> 1, wc = wid & 1;
    const int blockRow = blockIdx.x * 128;
    const int blockCol = blockIdx.y * 128;

    f32x4 acc[4][4] = {};

    for (int k0 = 0; k0 < 256; k0 += 32) {
        #pragma unroll
        for (int t = 0; t < 2; ++t) {
            int c   = t * 256 + wid * 64 + lane;   // 16B-chunk index
            int row = c >> 2, ko = (c & 3) * 8;
            load_lds16(A  + (size_t)(blockRow + row) * 256 + k0 + ko,
                       As + (size_t)(t * 256 + wid * 64) * 8);
            load_lds16(BT + (size_t)(blockCol + row) * 256 + k0 + ko,
                       Bs + (size_t)(t * 256 + wid * 64) * 8);
        }
        __syncthreads();
        bf16x8 af[4], bfr[4];
        #pragma unroll
        for (int m = 0; m < 4; ++m)
            af[m] = *(const bf16x8*)&As[(wr * 64 + m * 16 + l15) * 32 + l4 * 8];
        #pragma unroll
        for (int n = 0; n < 4; ++n)
            bfr[n] = *(const bf16x8*)&Bs[(wc * 64 + n * 16 + l15) * 32 + l4 * 8];
        #pragma unroll
        for (int m = 0; m < 4; ++m)
            #pragma unroll
            for (int n = 0; n < 4; ++n)
                acc[m][n] = __builtin_amdgcn_mfma_f32_16x16x32_bf16(af[m], bfr[n], acc[m][n], 0, 0, 0);
        __syncthreads();
    }

    #pragma unroll
    for (int m = 0; m < 4; ++m) {
        #pragma unroll
        for (int r = 0; r < 4; ++r) {
            int row = blockRow + wr * 64 + m * 16 + l4 * 4 + r;
            if (row >= M) continue;
            #pragma unroll
            for (int n = 0; n < 4; ++n) {
                int col = blockCol + wc * 64 + n * 16 + l15;
                float v = acc[m][n][r] + bias[col];
                if (MODE == 0) {
                    Cf[(size_t)row * 256 + col] = v;
                } else {
                    ushort b = f2b(v);
                    if (col < 256) {
                        qb[(size_t)row * 256 + col] = b;
                    } else if (col < 512) {
                        int d = col - 256;
                        kv[(size_t)row * 512 + (d >> 2) * 8 + (d & 3)] = b;
                    } else {
                        int d = col - 512;
                        kv[(size_t)row * 512 + (d >> 2) * 8 + 4 + (d & 3)] = b;
                    }
                }
            }
        }
    }
}

// ---------- CSR build ----------
__global__ void count_dst(const int* __restrict__ dst, int* __restrict__ counts, int E) {
    int i = blockIdx.x * blockDim.x + threadIdx.x;
    if (i < E) atomicAdd(&counts[dst[i]], 1);
}

// Single-workgroup exclusive scan, 1024 threads x 4 elements (int4).
__global__ void scan_offsets(const int* __restrict__ counts, int* __restrict__ offsets,
                             int* __restrict__ cursor, int N) {
    __shared__ int wsum[16];
    __shared__ int carry;
    int tid = threadIdx.x;
    int lane = tid & 63;
    int wid = tid >> 6;
    if (tid == 0) carry = 0;
    __syncthreads();
    for (int base = 0; base < N; base += 4096) {
        int i = base + tid * 4;
        int4 c = make_int4(0, 0, 0, 0);
        if (i < N) c = *(const int4*)(counts + i);   // N%4==0 assumed (padded alloc)
        int s = c.x + c.y + c.z + c.w;
        int x = s;
        #pragma unroll
        for (int d = 1; d < 64; d <<= 1) {
            int y = __shfl_up(x, d);
            if (lane >= d) x += y;
        }
        if (lane == 63) wsum[wid] = x;
        __syncthreads();
        if (wid == 0 && lane < 16) {
            int w = wsum[lane];
            #pragma unroll
            for (int d = 1; d < 16; d <<= 1) {
                int y = __shfl_up(w, d);
                if (lane >= d) w += y;
            }
            wsum[lane] = w;
        }
        __syncthreads();
        int pre = carry + (wid ? wsum[wid - 1] : 0) + (x - s);
        if (i < N) {
            int4 o;
            o.x = pre;
            o.y = pre + c.x;
            o.z = o.y + c.y;
            o.w = o.z + c.z;
            *(int4*)(offsets + i) = o;
            *(int4*)(cursor + i) = o;
        }
        int total = wsum[15];
        __syncthreads();
        if (tid == 0) carry += total;
        __syncthreads();
    }
    if (tid == 0) offsets[N] = carry;
}

__global__ void scatter_edges(const int* __restrict__ src, const int* __restrict__ dst,
                              int* __restrict__ cursor, int* __restrict__ csr_src, int E) {
    int i = blockIdx.x * blockDim.x + threadIdx.x;
    if (i < E) {
        int d = dst[i];
        int pos = atomicAdd(&cursor[d], 1);
        csr_src[pos] = src[i];
    }
}

// ---------- per-node attention: one wave per dst node ----------
// lane covers dims lane*4..+3 (head=lane>>3). kv interleaved: one 16B load
// gives {k0..k3, v0..v3}. 4-edge unroll, 2 accumulator chains.
// hbuf (bf16 h) doubles as residual source and h2 destination (row-exclusive).
__global__ void node_attn(const ushort* __restrict__ qb,
                          const ushort* __restrict__ kv,
                          const int* __restrict__ offsets,
                          const int* __restrict__ csr_src,
                          ushort* hbuf,
                          int N) {
    int wid = threadIdx.x >> 6, lane = threadIdx.x & 63;
    int n = blockIdx.x * 4 + wid;
    if (n >= N) return;
    int beg = offsets[n], end = offsets[n + 1];
    ushort4 qu = *(const ushort4*)(qb + (size_t)n * 256 + lane * 4);
    float qx = b2f(qu.x), qy = b2f(qu.y), qz = b2f(qu.z), qw = b2f(qu.w);

    float ax0 = 0.f, ay0 = 0.f, az0 = 0.f, aw0 = 0.f, den0 = 0.f;
    float ax1 = 0.f, ay1 = 0.f, az1 = 0.f, aw1 = 0.f, den1 = 0.f;
    int i = beg;
    for (; i + 4 <= end; i += 4) {
        int s0 = csr_src[i], s1 = csr_src[i + 1], s2 = csr_src[i + 2], s3 = csr_src[i + 3];
        ushort8 u0 = *(const ushort8*)(kv + (size_t)s0 * 512 + lane * 8);
        ushort8 u1 = *(const ushort8*)(kv + (size_t)s1 * 512 + lane * 8);
        ushort8 u2 = *(const ushort8*)(kv + (size_t)s2 * 512 + lane * 8);
        ushort8 u3 = *(const ushort8*)(kv + (size_t)s3 * 512 + lane * 8);
        float p0 = qx * b2f(u0[0]) + qy * b2f(u0[1]) + qz * b2f(u0[2]) + qw * b2f(u0[3]);
        float p1 = qx * b2f(u1[0]) + qy * b2f(u1[1]) + qz * b2f(u1[2]) + qw * b2f(u1[3]);
        float p2 = qx * b2f(u2[0]) + qy * b2f(u2[1]) + qz * b2f(u2[2]) + qw * b2f(u2[3]);
        float p3 = qx * b2f(u3[0]) + qy * b2f(u3[1]) + qz * b2f(u3[2]) + qw * b2f(u3[3]);
        p0 += __shfl_xor(p0, 1); p1 += __shfl_xor(p1, 1); p2 += __shfl_xor(p2, 1); p3 += __shfl_xor(p3, 1);
        p0 += __shfl_xor(p0, 2); p1 += __shfl_xor(p1, 2); p2 += __shfl_xor(p2, 2); p3 += __shfl_xor(p3, 2);
        p0 += __shfl_xor(p0, 4); p1 += __shfl_xor(p1, 4); p2 += __shfl_xor(p2, 4); p3 += __shfl_xor(p3, 4);
        float sc0 = __expf(p0 * SCALE), sc1 = __expf(p1 * SCALE);
        float sc2 = __expf(p2 * SCALE), sc3 = __expf(p3 * SCALE);
        den0 += sc0 + sc2;
        den1 += sc1 + sc3;
        ax0 += sc0 * b2f(u0[4]) + sc2 * b2f(u2[4]);
        ay0 += sc0 * b2f(u0[5]) + sc2 * b2f(u2[5]);
        az0 += sc0 * b2f(u0[6]) + sc2 * b2f(u2[6]);
        aw0 += sc0 * b2f(u0[7]) + sc2 * b2f(u2[7]);
        ax1 += sc1 * b2f(u1[4]) + sc3 * b2f(u3[4]);
        ay1 += sc1 * b2f(u1[5]) + sc3 * b2f(u3[5]);
        az1 += sc1 * b2f(u1[6]) + sc3 * b2f(u3[6]);
        aw1 += sc1 * b2f(u1[7]) + sc3 * b2f(u3[7]);
    }
    for (; i < end; ++i) {
        int s0 = csr_src[i];
        ushort8 u0 = *(const ushort8*)(kv + (size_t)s0 * 512 + lane * 8);
        float p0 = qx * b2f(u0[0]) + qy * b2f(u0[1]) + qz * b2f(u0[2]) + qw * b2f(u0[3]);
        p0 += __shfl_xor(p0, 1);
        p0 += __shfl_xor(p0, 2);
        p0 += __shfl_xor(p0, 4);
        float sc0 = __expf(p0 * SCALE);
        den0 += sc0;
        ax0 += sc0 * b2f(u0[4]); ay0 += sc0 * b2f(u0[5]);
        az0 += sc0 * b2f(u0[6]); aw0 += sc0 * b2f(u0[7]);
    }
    float den = den0 + den1;
    float inv = (end > beg) ? (1.0f / den) : 0.f;
    int head = lane >> 3;
    int d0 = (lane & 7) * 4;
    const ushort* hr = hbuf + (size_t)n * 256;
    float r0 = b2f(hr[(d0 + 0) * 8 + head]);
    float r1 = b2f(hr[(d0 + 1) * 8 + head]);
    float r2 = b2f(hr[(d0 + 2) * 8 + head]);
    float r3 = b2f(hr[(d0 + 3) * 8 + head]);
    ushort4 o;
    o.x = f2b((ax0 + ax1) * inv + r0);
    o.y = f2b((ay0 + ay1) * inv + r1);
    o.z = f2b((az0 + az1) * inv + r2);
    o.w = f2b((aw0 + aw1) * inv + r3);
    *(ushort4*)(hbuf + (size_t)n * 256 + lane * 4) = o;
}

extern "C" void kernel_launch(void* const* d_in, const int* in_sizes, int n_in,
                              void* d_out, int out_size, void* d_ws, size_t ws_size,
                              hipStream_t stream) {
    const float* h     = (const float*)d_in[0];
    const int*   src   = (const int*)d_in[1];
    const int*   dst   = (const int*)d_in[2];
    const float* W_qkv = (const float*)d_in[3];
    const float* b_qkv = (const float*)d_in[4];
    const float* W_out = (const float*)d_in[5];
    const float* b_out = (const float*)d_in[6];
    float* out = (float*)d_out;

    int N = in_sizes[0] / 256;
    int E = in_sizes[1];
    int Mpad = (N + 127) & ~127;
    int No   = (N + 16) & ~15;          // padded int stride, keeps int4 alignment

    ushort* qb   = (ushort*)d_ws;                      // Mpad*256 bf16
    ushort* kv   = qb + (size_t)Mpad * 256;            // Mpad*512 bf16 (interleaved)
    ushort* Abf  = kv + (size_t)Mpad * 512;            // Mpad*256 bf16 (h, then h2)
    ushort* WTq  = Abf + (size_t)Mpad * 256;           // 768*256
    ushort* WTo  = WTq + 768 * 256;                    // 256*256
    int* counts  = (int*)(WTo + 256 * 256);            // No
    int* offsets = counts + No;                        // No + 1 (uses N+1)
    int* cursor  = offsets + No;                       // No
    int* csr_src = cursor + No;                        // E

    hipMemsetAsync(counts, 0, (size_t)No * sizeof(int), stream);

    conv_bf16<<<(N * 64 + 255) / 256, 256, 0, stream>>>(h, Abf, N * 64);
    transpose_wqkv<<<768, 256, 0, stream>>>(W_qkv, WTq);
    transpose_wout<<<256, 256, 0, stream>>>(W_out, WTo);

    count_dst<<<(E + 255) / 256, 256, 0, stream>>>(dst, counts, E);
    scan_offsets<<<1, 1024, 0, stream>>>(counts, offsets, cursor, N);
    scatter_edges<<<(E + 255) / 256, 256, 0, stream>>>(src, dst, cursor, csr_src, E);

    dim3 g1(Mpad / 128, 6);
    gemm_mfma<1><<<g1, 256, 0, stream>>>(Abf, WTq, b_qkv, nullptr, qb, kv, N);

    node_attn<<<(N + 3) / 4, 256, 0, stream>>>(qb, kv, offsets, csr_src, Abf, N);

    dim3 g2(Mpad / 128, 2);
    gemm_mfma<0><<<g2, 256, 0, stream>>>(Abf, WTo, b_out, out, nullptr, nullptr, N);
}